// Round 6
// baseline (25996.933 us; speedup 1.0000x reference)
//
#include <hip/hip_runtime.h>
#include <hip/hip_fp16.h>

// TKANCell B=64,T=2048,D=128,U=128,NS=3 — fp32 in/out. 64 independent chains
// (tf.reshape routes sub-row r=3b'+j to batch b'=r/3). R5: 21.8ms, no spills,
// fp16/ws path confirmed (ws>=393KB), but 6 barriers x exposed L2 latency at
// 2 waves/SIMD. R6: 768-thr WGs (3 waves/SIMD), 4 barriers/step, shfl
// reductions, phase-A weights (Wr/Wh fp16) REGISTER-RESIDENT (t-invariant),
// x-projections precomputed for all T into ws by a parallel pre-GEMM
// (MODE 0, needs ws>=202MB) with 16-step-chunk fallback (MODE 1, ws>=393KB)
// and fp32-stream fallback (MODE 2). LDS_Block_Size tells which mode ran.

#define TT 2048
#define BB 64

typedef unsigned int u32;

__device__ __forceinline__ float sigf(float x) { return 1.f / (1.f + __expf(-x)); }
__device__ __forceinline__ float tanh_(float x) { return 2.f / (1.f + __expf(-2.f * x)) - 1.f; }
__device__ __forceinline__ float2 h2f2(u32 u) {
    __half2 h = *(__half2*)&u;
    return __half22float2(h);
}
__device__ __forceinline__ uint2 packh(float4 a) {
    __half2 lo = __floats2half2_rn(a.x, a.y), hi = __floats2half2_rn(a.z, a.w);
    uint2 r;
    r.x = *(u32*)&lo;
    r.y = *(u32*)&hi;
    return r;
}
__device__ __forceinline__ void red4(float4& a, int m) {
    a.x += __shfl_xor(a.x, m);
    a.y += __shfl_xor(a.y, m);
    a.z += __shfl_xor(a.z, m);
    a.w += __shfl_xor(a.w, m);
}

// fp16 copy of Wr|Wh|Dw|Aw (each 49152 elems, layout preserved) into ws.
__global__ __launch_bounds__(512) void convert_w(
    const float* __restrict__ Wr, const float* __restrict__ Wh,
    const float* __restrict__ Dw, const float* __restrict__ Aw,
    __half* __restrict__ dst) {
    int g = blockIdx.x * 512 + threadIdx.x;  // 0..196607
    int seg = g / 49152, idx = g % 49152;
    const float* src = (seg == 0) ? Wr : (seg == 1) ? Wh : (seg == 2) ? Dw : Aw;
    dst[g] = __float2half(src[idx]);
}

// Pre-GEMM (MODE 0): gxh[b][t][q(192) as uint2] = quad q of
// [x_b@Wk (q<96) | x_{(3b+j)%64}@Wx_nj (q>=96)]  — fp16, no bias.
__global__ __launch_bounds__(192, 1) void prege(
    const float* __restrict__ xg, const float* __restrict__ Wk,
    const float* __restrict__ Wx, uint2* __restrict__ gxh) {
    const int bp = blockIdx.x, t0 = blockIdx.y * 32, tid = threadIdx.x;
    __shared__ float xs[4][32][128];
    for (int f = tid; f < 4096; f += 192) {
        int v_ = f >> 10, r = f & 1023, ti = r >> 5, kq = r & 31;
        int row = (v_ == 0) ? bp : ((3 * bp + (v_ - 1)) & 63);
        float4 w = ((const float4*)(xg + ((size_t)row * TT + t0 + ti) * 128))[kq];
        *(float4*)&xs[v_][ti][kq * 4] = w;
    }
    __syncthreads();
    const int q = tid;
    const float4* Wp;
    int baseq, strq;
    const float* vb;
    if (q < 96) {
        Wp = (const float4*)Wk; baseq = q; strq = 96; vb = &xs[0][0][0];
    } else {
        int j = (q - 96) >> 5, qi = (q - 96) & 31, nj = (3 * bp + j) >> 6;
        Wp = (const float4*)Wx; baseq = nj * 4096 + qi; strq = 32;
        vb = &xs[1 + j][0][0];
    }
    for (int hf = 0; hf < 2; ++hf) {
        float4 acc[16];
#pragma unroll
        for (int i = 0; i < 16; ++i) acc[i] = make_float4(0.f, 0.f, 0.f, 0.f);
        int tb = hf * 16;
#pragma unroll 4
        for (int k = 0; k < 128; ++k) {
            float4 w = Wp[baseq + k * strq];
#pragma unroll
            for (int i = 0; i < 16; ++i) {
                float xv = vb[(tb + i) * 128 + k];
                acc[i].x += w.x * xv; acc[i].y += w.y * xv;
                acc[i].z += w.z * xv; acc[i].w += w.w * xv;
            }
        }
#pragma unroll
        for (int i = 0; i < 16; ++i)
            gxh[((size_t)bp * TT + t0 + tb + i) * 192 + q] = packh(acc[i]);
    }
}

// MODE: 0 = pre-GEMM gx from ws (fp16 weights); 1 = chunk-in-kernel (fp16);
//       2 = chunk-in-kernel, fp32 streamed weights (no ws).
template <int MODE>
__global__ __launch_bounds__(768, 1) void tkan(
    const float* __restrict__ xg, const float* __restrict__ Wk,
    const float* __restrict__ Wr, const float* __restrict__ bias,
    const float* __restrict__ Wx, const float* __restrict__ Wh,
    const float* __restrict__ stk, const float* __restrict__ Dw,
    const float* __restrict__ Db, const float* __restrict__ Aw,
    const float* __restrict__ Ab, const __half* __restrict__ wt,
    const uint2* __restrict__ gxg, float* __restrict__ outp) {
    const int bp = blockIdx.x, tid = threadIdx.x;
    const int lane = tid & 63;

    __shared__ float hS[128], cS[128], tcS[128];
    __shared__ float sS[384], aS[384], gS[384], pS[384];
    __shared__ float yS[128];
    __shared__ float biasL[384], DbL[384], AbL[128];
    __shared__ float stkj[6][128];
    __shared__ float xC[MODE == 0 ? 1 : 4][MODE == 0 ? 1 : 16][128];
    __shared__ uint2 gaL[MODE == 0 ? 1 : 16][MODE == 0 ? 1 : 192];

    const uint2* wt2 = (const uint2*)wt;  // Wr@0, Wh@12288, Dw@24576, Aw@36864

    // ---- init
    if (tid < 128) { hS[tid] = 0.f; cS[tid] = 0.f; AbL[tid] = Ab[tid]; }
    if (tid < 384) {
        sS[tid] = 0.f;
        biasL[tid] = bias[tid];
        int j = tid >> 7, o = tid & 127, nj = (3 * bp + j) >> 6;
        DbL[tid] = Db[nj * 128 + o];
    }
    {
        int jj = tid >> 7, o = tid & 127;      // jj 0..5
        int j = jj >> 1, wh = jj & 1, nj = (3 * bp + j) >> 6;
        stkj[jj][o] = stk[nj * 256 + wh * 128 + o];
    }

    // ---- phase-A task geometry (fixed per thread)
    const int qa = (tid >> 6) * 16 + (tid & 15);  // 0..191
    const int ksa = (tid >> 4) & 3;
    const int k0a = ksa * 32;
    int baseA, strA;
    const float* actA;
    const float4* WAf;
    if (qa < 96) {
        baseA = qa + k0a * 96; strA = 96;
        actA = hS + k0a;
        WAf = (const float4*)Wr;
    } else {
        int j = (qa - 96) >> 5, qi = (qa - 96) & 31, nj = (3 * bp + j) >> 6;
        baseA = 12288 + nj * 4096 + qi + k0a * 32; strA = 32;
        actA = sS + j * 128 + k0a;
        WAf = (const float4*)Wh;
    }
    int baseA2 = (qa < 96) ? (qa + k0a * 96)
                           : (((3 * bp + ((qa - 96) >> 5)) >> 6) * 4096 +
                              ((qa - 96) & 31) + k0a * 32);

    // resident phase-A weights (fp16 modes)
    uint2 wA[32];
    if (MODE < 2) {
#pragma unroll
        for (int k = 0; k < 32; ++k) wA[k] = wt2[baseA + k * strA];
    }

    // phase-B geometry
    const int qb = (tid >> 6) * 8 + (tid & 7);  // 0..95
    const int ksb = (tid >> 3) & 7;
    const int k0b = ksb * 16;
    const int jb = qb >> 5, qib = qb & 31, njb = (3 * bp + jb) >> 6;

    // MODE0: gx prefetch register
    uint2 gcur = make_uint2(0u, 0u);
    if (MODE == 0 && ksa == 0) gcur = gxg[((size_t)bp * TT) * 192 + qa];

    __syncthreads();

    for (int t = 0; t < TT; ++t) {
        // ===== chunk phase (MODE 1/2): x-projections for 16 steps =====
        if (MODE != 0 && (t & 15) == 0) {
            for (int f = tid; f < 2048; f += 768) {
                int v_ = f >> 9, r = f & 511, ti = r >> 5, kq = r & 31;
                int row = (v_ == 0) ? bp : ((3 * bp + (v_ - 1)) & 63);
                float4 w = ((const float4*)(xg + ((size_t)row * TT + t + ti) * 128))[kq];
                *(float4*)&xC[v_][ti][kq * 4] = w;
            }
            __syncthreads();
            {
                int q = tid % 192, tb = tid / 192;  // tb 0..3
                float4 a0 = make_float4(0, 0, 0, 0), a1 = a0, a2 = a0, a3 = a0;
                const float4* Wp;
                int bq, sq;
                const float* vb;
                if (q < 96) {
                    Wp = (const float4*)Wk; bq = q; sq = 96;
                    vb = &xC[0][tb * 4][0];
                } else {
                    int j = (q - 96) >> 5, qi = (q - 96) & 31, nj = (3 * bp + j) >> 6;
                    Wp = (const float4*)Wx; bq = nj * 4096 + qi; sq = 32;
                    vb = &xC[1 + j][tb * 4][0];
                }
#pragma unroll 4
                for (int k = 0; k < 128; ++k) {
                    float4 w = Wp[bq + k * sq];
                    float x0 = vb[k], x1 = vb[128 + k], x2 = vb[256 + k], x3 = vb[384 + k];
                    a0.x += w.x * x0; a0.y += w.y * x0; a0.z += w.z * x0; a0.w += w.w * x0;
                    a1.x += w.x * x1; a1.y += w.y * x1; a1.z += w.z * x1; a1.w += w.w * x1;
                    a2.x += w.x * x2; a2.y += w.y * x2; a2.z += w.z * x2; a2.w += w.w * x2;
                    a3.x += w.x * x3; a3.y += w.y * x3; a3.z += w.z * x3; a3.w += w.w * x3;
                }
                gaL[tb * 4 + 0][q] = packh(a0);
                gaL[tb * 4 + 1][q] = packh(a1);
                gaL[tb * 4 + 2][q] = packh(a2);
                gaL[tb * 4 + 3][q] = packh(a3);
            }
            __syncthreads();
        }

        // ===== Phase A: Wr·h + Wh·s (K-split 4, shfl-reduce 16/32) =====
        {
            float4 acc = make_float4(0, 0, 0, 0);
            if (MODE < 2) {
#pragma unroll
                for (int k = 0; k < 32; ++k) {
                    uint2 w = wA[k];
                    float a = actA[k];
                    float2 lo = h2f2(w.x), hi = h2f2(w.y);
                    acc.x += lo.x * a; acc.y += lo.y * a;
                    acc.z += hi.x * a; acc.w += hi.y * a;
                }
            } else {
#pragma unroll 8
                for (int k = 0; k < 32; ++k) {
                    float4 w = WAf[baseA2 + k * strA];
                    float a = actA[k];
                    acc.x += w.x * a; acc.y += w.y * a;
                    acc.z += w.z * a; acc.w += w.w * a;
                }
            }
            red4(acc, 16);
            red4(acc, 32);
            if (ksa == 0) {
                uint2 gq = (MODE == 0) ? gcur : gaL[t & 15][qa];
                float2 lo = h2f2(gq.x), hi = h2f2(gq.y);
                if (qa < 96) {
                    float4 b4 = *(float4*)&biasL[4 * qa];
                    float4 r;
                    r.x = acc.x + lo.x + b4.x; r.y = acc.y + lo.y + b4.y;
                    r.z = acc.z + hi.x + b4.z; r.w = acc.w + hi.y + b4.w;
                    *(float4*)&gS[4 * qa] = r;
                } else {
                    int cq = qa - 96;
                    float4 r;
                    r.x = acc.x + lo.x; r.y = acc.y + lo.y;
                    r.z = acc.z + hi.x; r.w = acc.w + hi.y;
                    *(float4*)&aS[4 * cq] = r;
                }
                if (MODE == 0) {
                    int tn = (t + 1 < TT) ? t + 1 : t;
                    gcur = gxg[((size_t)bp * TT + tn) * 192 + qa];
                }
            }
        }
        __syncthreads();

        // ===== Phase B: p-partials = a@Dw (K-split 8, shfl 8/16/32) =====
        {
            float4 acc = make_float4(0, 0, 0, 0);
            if (MODE < 2) {
#pragma unroll
                for (int k = 0; k < 16; ++k) {
                    uint2 w = wt2[24576 + njb * 4096 + qib + (k0b + k) * 32];
                    float a = aS[jb * 128 + k0b + k];
                    float2 lo = h2f2(w.x), hi = h2f2(w.y);
                    acc.x += lo.x * a; acc.y += lo.y * a;
                    acc.z += hi.x * a; acc.w += hi.y * a;
                }
            } else {
#pragma unroll 8
                for (int k = 0; k < 16; ++k) {
                    float4 w = ((const float4*)Dw)[njb * 4096 + qib + (k0b + k) * 32];
                    float a = aS[jb * 128 + k0b + k];
                    acc.x += w.x * a; acc.y += w.y * a;
                    acc.z += w.z * a; acc.w += w.w * a;
                }
            }
            red4(acc, 8);
            red4(acc, 16);
            red4(acc, 32);
            if (lane < 8) {
                float4 db = *(float4*)&DbL[4 * qb];
                float4 r;
                r.x = fmaxf(acc.x + db.x, 0.f);
                r.y = fmaxf(acc.y + db.y, 0.f);
                r.z = fmaxf(acc.z + db.z, 0.f);
                r.w = fmaxf(acc.w + db.w, 0.f);
                *(float4*)&pS[4 * qb] = r;
            }
        }
        __syncthreads();

        // ===== Phase C: y-partials = p@Aw ; s-update ; c-update =====
        if (tid < 256) {
            int qc = (tid >> 6) * 8 + (tid & 7);  // 0..31
            int ksc = (tid >> 3) & 7, k0c = ksc * 48;
            float4 acc = make_float4(0, 0, 0, 0);
            if (MODE < 2) {
#pragma unroll 16
                for (int k = 0; k < 48; ++k) {
                    uint2 w = wt2[36864 + qc + (k0c + k) * 32];
                    float a = pS[k0c + k];
                    float2 lo = h2f2(w.x), hi = h2f2(w.y);
                    acc.x += lo.x * a; acc.y += lo.y * a;
                    acc.z += hi.x * a; acc.w += hi.y * a;
                }
            } else {
#pragma unroll 8
                for (int k = 0; k < 48; ++k) {
                    float4 w = ((const float4*)Aw)[qc + (k0c + k) * 32];
                    float a = pS[k0c + k];
                    acc.x += w.x * a; acc.y += w.y * a;
                    acc.z += w.z * a; acc.w += w.w * a;
                }
            }
            red4(acc, 8);
            red4(acc, 16);
            red4(acc, 32);
            if (lane < 8) *(float4*)&yS[4 * qc] = acc;
        } else if (tid < 640) {
            int e = tid - 256, jj = e >> 7, o = e & 127;
            sS[e] = stkj[2 * jj][o] * pS[e] + stkj[2 * jj + 1][o] * sS[e];
        } else {
            int u = tid - 640;
            float gi = sigf(gS[u]);
            float gf = sigf(gS[128 + u]);
            float gc = sigf(gS[256 + u]);
            float cn = gf * cS[u] + gi * tanh_(gc);
            cS[u] = cn;
            tcS[u] = tanh_(cn);
        }
        __syncthreads();

        // ===== Phase D: finalize h, write out =====
        if (tid < 128) {
            float hn = sigf(yS[tid] + AbL[tid]) * tcS[tid];
            hS[tid] = hn;
            outp[((size_t)bp * TT + t) * 128 + tid] = hn;
        }
        __syncthreads();
    }
}

extern "C" void kernel_launch(void* const* d_in, const int* in_sizes, int n_in,
                              void* d_out, int out_size, void* d_ws, size_t ws_size,
                              hipStream_t stream) {
    const float* x    = (const float*)d_in[0];
    const float* Wk   = (const float*)d_in[1];
    const float* Wr   = (const float*)d_in[2];
    const float* bias = (const float*)d_in[3];
    const float* Wx   = (const float*)d_in[4];
    const float* Wh   = (const float*)d_in[5];
    const float* stk  = (const float*)d_in[6];
    const float* Dw   = (const float*)d_in[7];
    const float* Db   = (const float*)d_in[8];
    const float* Aw   = (const float*)d_in[9];
    const float* Ab   = (const float*)d_in[10];
    float* outp = (float*)d_out;

    const size_t needW = 196608 * sizeof(__half);                 // 393,216 B
    const size_t needG = needW + (size_t)BB * TT * 192 * 8;       // +201.3 MB

    if (ws_size >= needG) {
        __half* wt = (__half*)d_ws;
        uint2* gxh = (uint2*)((char*)d_ws + needW);
        convert_w<<<dim3(384), dim3(512), 0, stream>>>(Wr, Wh, Dw, Aw, wt);
        prege<<<dim3(BB, TT / 32), dim3(192), 0, stream>>>(x, Wk, Wx, gxh);
        tkan<0><<<dim3(BB), dim3(768), 0, stream>>>(
            x, Wk, Wr, bias, Wx, Wh, stk, Dw, Db, Aw, Ab, wt, gxh, outp);
    } else if (ws_size >= needW) {
        __half* wt = (__half*)d_ws;
        convert_w<<<dim3(384), dim3(512), 0, stream>>>(Wr, Wh, Dw, Aw, wt);
        tkan<1><<<dim3(BB), dim3(768), 0, stream>>>(
            x, Wk, Wr, bias, Wx, Wh, stk, Dw, Db, Aw, Ab, wt, (const uint2*)nullptr,
            outp);
    } else {
        tkan<2><<<dim3(BB), dim3(768), 0, stream>>>(
            x, Wk, Wr, bias, Wx, Wh, stk, Dw, Db, Aw, Ab, (const __half*)nullptr,
            (const uint2*)nullptr, outp);
    }
}